// Round 1
// baseline (512.826 us; speedup 1.0000x reference)
//
#include <hip/hip_runtime.h>
#include <stdint.h>

#define Bb   2
#define Tt   2048
#define Cc_  2048
#define Hh   16
#define Dd   128
#define Mm_  4096            // B*T
#define N1   6144            // 3*C
#define EPSf 1.1920929e-07f
#define SCALE (1.0f/128.0f)  // reference uses 1/D, not 1/sqrt(D)

typedef __bf16 bf16;
typedef __attribute__((ext_vector_type(8))) __bf16 bf16x8;
typedef __attribute__((ext_vector_type(4))) float  f32x4;

// ---- async global->LDS, width 16. LDS dest semantics: wave-uniform base +
// lane*16 (m104/m108) -- lane's lds ptr must equal base + lane*16.
__device__ __forceinline__ void gl_lds16(const bf16* g, bf16* l) {
  __builtin_amdgcn_global_load_lds(
      (const __attribute__((address_space(1))) unsigned int*)g,
      (__attribute__((address_space(3))) unsigned int*)l, 16, 0, 0);
}

// ------------------------------------------------------------------ cvt x->bf16
__global__ __launch_bounds__(256) void cvt_bf16(const float* __restrict__ in,
                                                bf16* __restrict__ out, int n) {
  int i = (blockIdx.x * 256 + threadIdx.x) * 4;
  if (i >= n) return;
  float4 v = *(const float4*)(in + i);
  union { bf16 h[4]; uint2 u; } o;
  o.h[0] = (bf16)v.x; o.h[1] = (bf16)v.y; o.h[2] = (bf16)v.z; o.h[3] = (bf16)v.w;
  *(uint2*)(out + i) = o.u;
}

// -------------------------------------------- transpose+convert: [R][Cc]f32 -> [Cc][R]bf16
__global__ __launch_bounds__(256) void transpose_cvt(const float* __restrict__ in,
                                                     bf16* __restrict__ out,
                                                     int R, int Cc) {
  __shared__ float tile[64][65];
  int c0 = blockIdx.x * 64, r0 = blockIdx.y * 64;
  int tid = threadIdx.x;
#pragma unroll
  for (int j = 0; j < 16; ++j) {
    int idx = tid + j * 256;
    int r = idx >> 6, c = idx & 63;
    tile[r][c] = in[(size_t)(r0 + r) * Cc + c0 + c];
  }
  __syncthreads();
#pragma unroll
  for (int j = 0; j < 16; ++j) {
    int idx = tid + j * 256;
    int rr = idx & 63, cc = idx >> 6;
    out[(size_t)(c0 + cc) * R + r0 + rr] = (bf16)tile[rr][cc];
  }
}

// ------------------------------------------------------------------ GEMM
// C[M][N] = A[M][K] * Bt[N][K]^T, bf16 in, OutT out. 128x128 tile, BK=64,
// 4 waves (2x2), each wave 64x64 via 4x4 MFMA 16x16x32 tiles.
// LDS tiles XOR-swizzled at 16B-chunk granularity: slot(r,cc) holds global
// chunk cc^(r&7)  -> conflict-free ds_read_b128 fragment reads.
template <typename OutT>
__global__ __launch_bounds__(256) void gemm_bf16(const bf16* __restrict__ A,
                                                 const bf16* __restrict__ Bt,
                                                 OutT* __restrict__ Cm,
                                                 int Nn, int Kk) {
  __shared__ __align__(16) bf16 As[128 * 64];
  __shared__ __align__(16) bf16 Bs[128 * 64];
  const int tid = threadIdx.x;
  const int wave = tid >> 6, lane = tid & 63;
  const int quad = lane >> 4, li = lane & 15;
  const int wm = wave >> 1, wn = wave & 1;
  const int m0 = blockIdx.y * 128, n0 = blockIdx.x * 128;

  f32x4 acc[4][4] = {};

  for (int kt = 0; kt < Kk; kt += 64) {
    __syncthreads();
#pragma unroll
    for (int j = 0; j < 4; ++j) {
      int c = j * 256 + tid;
      int r = c >> 3, cc = c & 7;
      int gc = ((cc ^ (r & 7)) << 3);
      gl_lds16(A + (size_t)(m0 + r) * Kk + kt + gc, &As[c * 8]);
      gl_lds16(Bt + (size_t)(n0 + r) * Kk + kt + gc, &Bs[c * 8]);
    }
    __syncthreads();
#pragma unroll
    for (int kc = 0; kc < 2; ++kc) {
      bf16x8 af[4], bfr[4];
#pragma unroll
      for (int t = 0; t < 4; ++t) {
        int rowa = wm * 64 + t * 16 + li;
        af[t] = *(const bf16x8*)&As[rowa * 64 + (((kc * 4 + quad) ^ (rowa & 7)) << 3)];
        int rowb = wn * 64 + t * 16 + li;
        bfr[t] = *(const bf16x8*)&Bs[rowb * 64 + (((kc * 4 + quad) ^ (rowb & 7)) << 3)];
      }
#pragma unroll
      for (int mi = 0; mi < 4; ++mi)
#pragma unroll
        for (int ni = 0; ni < 4; ++ni)
          acc[mi][ni] = __builtin_amdgcn_mfma_f32_16x16x32_bf16(af[mi], bfr[ni],
                                                                acc[mi][ni], 0, 0, 0);
    }
  }
  // epilogue: C/D layout col=li, row=quad*4+reg
#pragma unroll
  for (int mi = 0; mi < 4; ++mi) {
    int row = m0 + wm * 64 + mi * 16 + quad * 4;
#pragma unroll
    for (int ni = 0; ni < 4; ++ni) {
      int col = n0 + wn * 64 + ni * 16 + li;
#pragma unroll
      for (int r = 0; r < 4; ++r)
        Cm[(size_t)(row + r) * Nn + col] = (OutT)acc[mi][ni][r];
    }
  }
}

// ------------------------------------------- RMSNorm + RoPE + rearrange
// qkv[M][6144]bf16 -> Q,K [bh][T][D] (normed+roped), V [bh][T][D] bf16.
// One wave per (b,t,h); lane d in [0,64) handles d and d+64 (RoPE pair).
__global__ __launch_bounds__(256) void norm_rope_rearrange(
    const bf16* __restrict__ qkv, const float* __restrict__ qw,
    const float* __restrict__ kw, bf16* __restrict__ Qg,
    bf16* __restrict__ Kg, bf16* __restrict__ Vg) {
  int unit = blockIdx.x * 4 + (threadIdx.x >> 6);  // (b*T + t)*H + h
  int lane = threadIdx.x & 63;
  int h = unit & 15;
  int bt = unit >> 4;
  int t = bt & 2047, b = bt >> 11;
  const bf16* base = qkv + (size_t)bt * N1 + h * Dd;
  float q1 = (float)base[lane], q2 = (float)base[lane + 64];
  float k1 = (float)base[Cc_ + lane], k2 = (float)base[Cc_ + lane + 64];
  float v1 = (float)base[2 * Cc_ + lane], v2 = (float)base[2 * Cc_ + lane + 64];
  float sq = q1 * q1 + q2 * q2;
  float sk = k1 * k1 + k2 * k2;
#pragma unroll
  for (int o = 1; o < 64; o <<= 1) { sq += __shfl_xor(sq, o); sk += __shfl_xor(sk, o); }
  float rq = rsqrtf(sq * (1.0f / 128.0f) + EPSf);
  float rk = rsqrtf(sk * (1.0f / 128.0f) + EPSf);
  q1 *= rq * qw[lane]; q2 *= rq * qw[lane + 64];
  k1 *= rk * kw[lane]; k2 *= rk * kw[lane + 64];
  // RoPE: inv_freq = 1e6^(-lane/64); cos/sin shared between d and d+64
  float invf = exp2f((float)lane * (-19.9315685693241740f / 64.0f));
  float ang = (float)t * invf;
  float sn, cs;
  sincosf(ang, &sn, &cs);
  float qo1 = q1 * cs - q2 * sn, qo2 = q2 * cs + q1 * sn;
  float ko1 = k1 * cs - k2 * sn, ko2 = k2 * cs + k1 * sn;
  size_t o1 = ((size_t)(b * Hh + h) * Tt + t) * Dd + lane;
  Qg[o1] = (bf16)qo1; Qg[o1 + 64] = (bf16)qo2;
  Kg[o1] = (bf16)ko1; Kg[o1 + 64] = (bf16)ko2;
  Vg[o1] = (bf16)v1;  Vg[o1 + 64] = (bf16)v2;
}

// ------------------------------------------------------------------ attention
// Flash-style. Block = one (b,h) x 64 q-rows; wave handles 16 q-rows.
// K staged [64][128] via global_load_lds (XOR swizzle); V staged transposed
// into Vt[128][72] (padded) via per-lane writes; P round-trips through LDS
// (C-layout -> A-layout, m120 pattern).
__global__ __launch_bounds__(256) void attn(const bf16* __restrict__ Qg,
                                            const bf16* __restrict__ Kg,
                                            const bf16* __restrict__ Vg,
                                            bf16* __restrict__ Yg) {
  __shared__ __align__(16) bf16 Kl[64 * 128];
  __shared__ __align__(16) bf16 Vt[128 * 72];
  __shared__ __align__(16) bf16 Pl[4 * 16 * 72];
  const int bh = blockIdx.x;
  const int qt = (int)gridDim.y - 1 - (int)blockIdx.y;  // long blocks first
  const int b = bh >> 4, h = bh & 15;
  const int tid = threadIdx.x, wave = tid >> 6, lane = tid & 63;
  const int quad = lane >> 4, li = lane & 15;
  const int q0 = qt * 64;

  // Q fragments (A-layout) straight from global, held for whole block
  const bf16* Qbase = Qg + ((size_t)bh * Tt + q0 + wave * 16 + li) * Dd;
  bf16x8 qf[4];
#pragma unroll
  for (int kc = 0; kc < 4; ++kc) qf[kc] = *(const bf16x8*)(Qbase + kc * 32 + quad * 8);

  f32x4 o[8] = {};
  float Mx[4] = {-1e30f, -1e30f, -1e30f, -1e30f};
  float L[4] = {};

  for (int kt = 0; kt <= qt; ++kt) {
    const int k0 = kt * 64;
    __syncthreads();  // previous iter's LDS reads done
    // stage K tile [64][128], swizzled
#pragma unroll
    for (int j = 0; j < 4; ++j) {
      int c = j * 256 + tid;
      int r = c >> 4, cc = c & 15;
      gl_lds16(Kg + ((size_t)bh * Tt + k0 + r) * Dd + ((cc ^ (r & 7)) << 3), &Kl[c * 8]);
    }
    // stage V transposed: Vt[d][k], rows padded to 72
#pragma unroll
    for (int j = 0; j < 4; ++j) {
      int c = j * 256 + tid;
      int k = c & 63, d0 = (c >> 6) * 8;
      bf16x8 v = *(const bf16x8*)(Vg + ((size_t)bh * Tt + k0 + k) * Dd + d0);
#pragma unroll
      for (int e = 0; e < 8; ++e) Vt[(d0 + e) * 72 + k] = v[e];
    }
    __syncthreads();
    // QK^T
    f32x4 s4[4] = {};
#pragma unroll
    for (int nt = 0; nt < 4; ++nt) {
      int key = nt * 16 + li;
#pragma unroll
      for (int kc = 0; kc < 4; ++kc) {
        bf16x8 kf = *(const bf16x8*)&Kl[key * 128 + (((kc * 4 + quad) ^ (key & 7)) << 3)];
        s4[nt] = __builtin_amdgcn_mfma_f32_16x16x32_bf16(qf[kc], kf, s4[nt], 0, 0, 0);
      }
    }
    // scale + causal mask (C-layout: row=quad*4+r local q, col=li local key)
    const bool diag = (kt == qt);
    float sv[4][4];
#pragma unroll
    for (int nt = 0; nt < 4; ++nt)
#pragma unroll
      for (int r = 0; r < 4; ++r) {
        float v = s4[nt][r] * SCALE;
        if (diag && (nt * 16 + li > wave * 16 + quad * 4 + r)) v = -1e30f;
        sv[nt][r] = v;
      }
    // online softmax, per row r (quad-local shuffle reduction over 16 lanes)
    float al[4];
#pragma unroll
    for (int r = 0; r < 4; ++r) {
      float m = fmaxf(fmaxf(sv[0][r], sv[1][r]), fmaxf(sv[2][r], sv[3][r]));
#pragma unroll
      for (int off = 1; off < 16; off <<= 1) m = fmaxf(m, __shfl_xor(m, off));
      float nm = fmaxf(Mx[r], m);
      al[r] = __expf(Mx[r] - nm);
      Mx[r] = nm;
      float s0 = 0.f;
#pragma unroll
      for (int nt = 0; nt < 4; ++nt) {
        sv[nt][r] = __expf(sv[nt][r] - nm);
        s0 += sv[nt][r];
      }
#pragma unroll
      for (int off = 1; off < 16; off <<= 1) s0 += __shfl_xor(s0, off);
      L[r] = L[r] * al[r] + s0;
    }
#pragma unroll
    for (int u = 0; u < 8; ++u)
#pragma unroll
      for (int r = 0; r < 4; ++r) o[u][r] *= al[r];
    // P: C-layout -> LDS -> A-layout (per-wave region; same-wave DS is in-order)
    bf16* Pw = &Pl[wave * 16 * 72];
#pragma unroll
    for (int nt = 0; nt < 4; ++nt)
#pragma unroll
      for (int r = 0; r < 4; ++r)
        Pw[(quad * 4 + r) * 72 + nt * 16 + li] = (bf16)sv[nt][r];
    // PV: o[16 q][128 d] += P[16][64] * V[64][128]
#pragma unroll
    for (int kc = 0; kc < 2; ++kc) {
      bf16x8 pf = *(const bf16x8*)&Pw[li * 72 + kc * 32 + quad * 8];
#pragma unroll
      for (int u = 0; u < 8; ++u) {
        bf16x8 vf = *(const bf16x8*)&Vt[(u * 16 + li) * 72 + kc * 32 + quad * 8];
        o[u] = __builtin_amdgcn_mfma_f32_16x16x32_bf16(pf, vf, o[u], 0, 0, 0);
      }
    }
  }
  // normalize + write Y [b*T + t][h*D + d] bf16
  float inv[4];
#pragma unroll
  for (int r = 0; r < 4; ++r) inv[r] = 1.0f / L[r];
  int trow = q0 + wave * 16 + quad * 4;
#pragma unroll
  for (int u = 0; u < 8; ++u) {
    int col = h * Dd + u * 16 + li;
#pragma unroll
    for (int r = 0; r < 4; ++r)
      Yg[(size_t)(b * Tt + trow + r) * Cc_ + col] = (bf16)(o[u][r] * inv[r]);
  }
}

// ------------------------------------------------------------------ launch
extern "C" void kernel_launch(void* const* d_in, const int* in_sizes, int n_in,
                              void* d_out, int out_size, void* d_ws, size_t ws_size,
                              hipStream_t stream) {
  const float* x      = (const float*)d_in[0];
  const float* w_qkv  = (const float*)d_in[1];
  const float* w_proj = (const float*)d_in[2];
  const float* qnw    = (const float*)d_in[3];
  const float* knw    = (const float*)d_in[4];
  float* out = (float*)d_out;

  // workspace partition (bf16 elements), ~160 MiB total
  bf16* xb     = (bf16*)d_ws;
  bf16* wqkvT  = xb + (size_t)Mm_ * Cc_;        //  16.8 MB
  bf16* wprojT = wqkvT + (size_t)N1 * Cc_;      //  25.2 MB
  bf16* qkv    = wprojT + (size_t)Cc_ * Cc_;    //   8.4 MB
  bf16* Qg     = qkv + (size_t)Mm_ * N1;        //  50.3 MB
  bf16* Kg     = Qg + (size_t)Bb * Hh * Tt * Dd;
  bf16* Vg     = Kg + (size_t)Bb * Hh * Tt * Dd;
  bf16* Yg     = Vg + (size_t)Bb * Hh * Tt * Dd;

  hipLaunchKernelGGL(cvt_bf16, dim3((Mm_ * Cc_ / 4) / 256), dim3(256), 0, stream,
                     x, xb, Mm_ * Cc_);
  hipLaunchKernelGGL(transpose_cvt, dim3(N1 / 64, Cc_ / 64), dim3(256), 0, stream,
                     w_qkv, wqkvT, Cc_, N1);
  hipLaunchKernelGGL(transpose_cvt, dim3(Cc_ / 64, Cc_ / 64), dim3(256), 0, stream,
                     w_proj, wprojT, Cc_, Cc_);
  hipLaunchKernelGGL(gemm_bf16<bf16>, dim3(N1 / 128, Mm_ / 128), dim3(256), 0, stream,
                     xb, wqkvT, qkv, N1, Cc_);
  hipLaunchKernelGGL(norm_rope_rearrange, dim3(Bb * Tt * Hh / 4), dim3(256), 0, stream,
                     qkv, qnw, knw, Qg, Kg, Vg);
  hipLaunchKernelGGL(attn, dim3(Bb * Hh, Tt / 64), dim3(256), 0, stream,
                     Qg, Kg, Vg, Yg);
  hipLaunchKernelGGL(gemm_bf16<float>, dim3(Cc_ / 128, Mm_ / 128), dim3(256), 0, stream,
                     Yg, wprojT, out, Cc_, Cc_);
}

// Round 2
// 456.471 us; speedup vs baseline: 1.1235x; 1.1235x over previous
//
#include <hip/hip_runtime.h>
#include <stdint.h>

#define Bb   2
#define Tt   2048
#define Cc_  2048
#define Hh   16
#define Dd   128
#define Mm_  4096            // B*T
#define N1   6144            // 3*C
#define EPSf 1.1920929e-07f
#define SCALE (1.0f/128.0f)  // reference uses 1/D, not 1/sqrt(D)

typedef __bf16 bf16;
typedef __attribute__((ext_vector_type(8))) __bf16 bf16x8;
typedef __attribute__((ext_vector_type(4))) float  f32x4;

// ---- async global->LDS, width 16. LDS dest semantics: wave-uniform base +
// lane*16 (m104/m108) -- lane's lds ptr must equal base + lane*16.
__device__ __forceinline__ void gl_lds16(const bf16* g, bf16* l) {
  __builtin_amdgcn_global_load_lds(
      (const __attribute__((address_space(1))) unsigned int*)g,
      (__attribute__((address_space(3))) unsigned int*)l, 16, 0, 0);
}

// ------------------------------------------------------------------ cvt x->bf16
__global__ __launch_bounds__(256) void cvt_bf16(const float* __restrict__ in,
                                                bf16* __restrict__ out, int n) {
  int i = (blockIdx.x * 256 + threadIdx.x) * 4;
  if (i >= n) return;
  float4 v = *(const float4*)(in + i);
  union { bf16 h[4]; uint2 u; } o;
  o.h[0] = (bf16)v.x; o.h[1] = (bf16)v.y; o.h[2] = (bf16)v.z; o.h[3] = (bf16)v.w;
  *(uint2*)(out + i) = o.u;
}

// -------------------------------------------- transpose+convert: [R][Cc]f32 -> [Cc][R]bf16
__global__ __launch_bounds__(256) void transpose_cvt(const float* __restrict__ in,
                                                     bf16* __restrict__ out,
                                                     int R, int Cc) {
  __shared__ float tile[64][65];
  int c0 = blockIdx.x * 64, r0 = blockIdx.y * 64;
  int tid = threadIdx.x;
#pragma unroll
  for (int j = 0; j < 16; ++j) {
    int idx = tid + j * 256;
    int r = idx >> 6, c = idx & 63;
    tile[r][c] = in[(size_t)(r0 + r) * Cc + c0 + c];
  }
  __syncthreads();
#pragma unroll
  for (int j = 0; j < 16; ++j) {
    int idx = tid + j * 256;
    int rr = idx & 63, cc = idx >> 6;
    out[(size_t)(c0 + cc) * R + r0 + rr] = (bf16)tile[rr][cc];
  }
}

// ----------------------------------- V transpose: [bh][T][D] -> [bh][D][T] bf16
__global__ __launch_bounds__(256) void vtrans(const bf16* __restrict__ V,
                                              bf16* __restrict__ Vt_) {
  __shared__ bf16 tile[64][72];
  int bh = blockIdx.z, t0 = blockIdx.x * 64, d0 = blockIdx.y * 64;
  int tid = threadIdx.x;
#pragma unroll
  for (int j = 0; j < 2; ++j) {
    int idx = (j * 256 + tid) * 8;
    int r = idx >> 6, c = idx & 63;  // r = t row, c = d col
    bf16x8 v = *(const bf16x8*)(V + ((size_t)bh * Tt + t0 + r) * Dd + d0 + c);
#pragma unroll
    for (int e = 0; e < 8; ++e) tile[r][c + e] = v[e];
  }
  __syncthreads();
#pragma unroll
  for (int j = 0; j < 2; ++j) {
    int idx = (j * 256 + tid) * 8;
    int dd = idx >> 6, tt = idx & 63;  // out row = d, 8 consecutive t
    bf16x8 v;
#pragma unroll
    for (int e = 0; e < 8; ++e) v[e] = tile[tt + e][dd];
    *(bf16x8*)(Vt_ + ((size_t)bh * Dd + d0 + dd) * Tt + t0 + tt) = v;
  }
}

// ------------------------------------------------------------------ GEMM
// C[M][N] = A[M][K] * Bt[N][K]^T, bf16 in, OutT out. 128x128 tile, BK=64,
// 4 waves (2x2), each wave 64x64 via 4x4 MFMA 16x16x32 tiles.
template <typename OutT>
__global__ __launch_bounds__(256) void gemm_bf16(const bf16* __restrict__ A,
                                                 const bf16* __restrict__ Bt,
                                                 OutT* __restrict__ Cm,
                                                 int Nn, int Kk) {
  __shared__ __align__(16) bf16 As[128 * 64];
  __shared__ __align__(16) bf16 Bs[128 * 64];
  const int tid = threadIdx.x;
  const int wave = tid >> 6, lane = tid & 63;
  const int quad = lane >> 4, li = lane & 15;
  const int wm = wave >> 1, wn = wave & 1;
  const int m0 = blockIdx.y * 128, n0 = blockIdx.x * 128;

  f32x4 acc[4][4] = {};

  for (int kt = 0; kt < Kk; kt += 64) {
    __syncthreads();
#pragma unroll
    for (int j = 0; j < 4; ++j) {
      int c = j * 256 + tid;
      int r = c >> 3, cc = c & 7;
      int gc = ((cc ^ (r & 7)) << 3);
      gl_lds16(A + (size_t)(m0 + r) * Kk + kt + gc, &As[c * 8]);
      gl_lds16(Bt + (size_t)(n0 + r) * Kk + kt + gc, &Bs[c * 8]);
    }
    __syncthreads();
#pragma unroll
    for (int kc = 0; kc < 2; ++kc) {
      bf16x8 af[4], bfr[4];
#pragma unroll
      for (int t = 0; t < 4; ++t) {
        int rowa = wm * 64 + t * 16 + li;
        af[t] = *(const bf16x8*)&As[rowa * 64 + (((kc * 4 + quad) ^ (rowa & 7)) << 3)];
        int rowb = wn * 64 + t * 16 + li;
        bfr[t] = *(const bf16x8*)&Bs[rowb * 64 + (((kc * 4 + quad) ^ (rowb & 7)) << 3)];
      }
#pragma unroll
      for (int mi = 0; mi < 4; ++mi)
#pragma unroll
        for (int ni = 0; ni < 4; ++ni)
          acc[mi][ni] = __builtin_amdgcn_mfma_f32_16x16x32_bf16(af[mi], bfr[ni],
                                                                acc[mi][ni], 0, 0, 0);
    }
  }
#pragma unroll
  for (int mi = 0; mi < 4; ++mi) {
    int row = m0 + wm * 64 + mi * 16 + quad * 4;
#pragma unroll
    for (int ni = 0; ni < 4; ++ni) {
      int col = n0 + wn * 64 + ni * 16 + li;
#pragma unroll
      for (int r = 0; r < 4; ++r)
        Cm[(size_t)(row + r) * Nn + col] = (OutT)acc[mi][ni][r];
    }
  }
}

// ------------------------------------------- RMSNorm + RoPE + rearrange
__global__ __launch_bounds__(256) void norm_rope_rearrange(
    const bf16* __restrict__ qkv, const float* __restrict__ qw,
    const float* __restrict__ kw, bf16* __restrict__ Qg,
    bf16* __restrict__ Kg, bf16* __restrict__ Vg) {
  int unit = blockIdx.x * 4 + (threadIdx.x >> 6);  // (b*T + t)*H + h
  int lane = threadIdx.x & 63;
  int h = unit & 15;
  int bt = unit >> 4;
  int t = bt & 2047, b = bt >> 11;
  const bf16* base = qkv + (size_t)bt * N1 + h * Dd;
  float q1 = (float)base[lane], q2 = (float)base[lane + 64];
  float k1 = (float)base[Cc_ + lane], k2 = (float)base[Cc_ + lane + 64];
  float v1 = (float)base[2 * Cc_ + lane], v2 = (float)base[2 * Cc_ + lane + 64];
  float sq = q1 * q1 + q2 * q2;
  float sk = k1 * k1 + k2 * k2;
#pragma unroll
  for (int o = 1; o < 64; o <<= 1) { sq += __shfl_xor(sq, o); sk += __shfl_xor(sk, o); }
  float rq = rsqrtf(sq * (1.0f / 128.0f) + EPSf);
  float rk = rsqrtf(sk * (1.0f / 128.0f) + EPSf);
  q1 *= rq * qw[lane]; q2 *= rq * qw[lane + 64];
  k1 *= rk * kw[lane]; k2 *= rk * kw[lane + 64];
  float invf = exp2f((float)lane * (-19.9315685693241740f / 64.0f));
  float ang = (float)t * invf;
  float sn, cs;
  sincosf(ang, &sn, &cs);
  float qo1 = q1 * cs - q2 * sn, qo2 = q2 * cs + q1 * sn;
  float ko1 = k1 * cs - k2 * sn, ko2 = k2 * cs + k1 * sn;
  size_t o1 = ((size_t)(b * Hh + h) * Tt + t) * Dd + lane;
  Qg[o1] = (bf16)qo1; Qg[o1 + 64] = (bf16)qo2;
  Kg[o1] = (bf16)ko1; Kg[o1 + 64] = (bf16)ko2;
  Vg[o1] = (bf16)v1;  Vg[o1 + 64] = (bf16)v2;
}

// ------------------------------------------------------------------ attention
// Pair-balanced flash: block = (bh, p) handles q-tiles qtA=p and qtB=31-p in
// ONE KV sweep (kt=0..qtB; tile B always, tile A when kt<=qtA). Every block
// does exactly 33 tile-applications -> uniform work, 512 blocks = 2/CU.
// K and V^T both staged via swizzled global_load_lds width-16.
__global__ __launch_bounds__(256, 2) void attn(const bf16* __restrict__ Qg,
                                               const bf16* __restrict__ Kg,
                                               const bf16* __restrict__ VgT,
                                               bf16* __restrict__ Yg) {
  __shared__ __align__(16) bf16 Kl[64 * 128];
  __shared__ __align__(16) bf16 Vl[128 * 64];
  __shared__ __align__(16) bf16 Pl[4 * 16 * 72];
  const int bh = blockIdx.x;
  const int p = blockIdx.y;
  const int qtA = p, qtB = (Tt / 64 - 1) - p;
  const int b = bh >> 4, h = bh & 15;
  const int tid = threadIdx.x, wave = tid >> 6, lane = tid & 63;
  const int quad = lane >> 4, li = lane & 15;

  // Q fragments (A-layout) for both tiles, held in regs for the whole block
  const bf16* QbA = Qg + ((size_t)bh * Tt + qtA * 64 + wave * 16 + li) * Dd;
  const bf16* QbB = Qg + ((size_t)bh * Tt + qtB * 64 + wave * 16 + li) * Dd;
  bf16x8 qfA[4], qfB[4];
#pragma unroll
  for (int kc = 0; kc < 4; ++kc) {
    qfA[kc] = *(const bf16x8*)(QbA + kc * 32 + quad * 8);
    qfB[kc] = *(const bf16x8*)(QbB + kc * 32 + quad * 8);
  }

  f32x4 oA[8] = {}, oB[8] = {};
  float MxA[4] = {-1e30f, -1e30f, -1e30f, -1e30f};
  float MxB[4] = {-1e30f, -1e30f, -1e30f, -1e30f};
  float LA[4] = {}, LB[4] = {};
  bf16* Pw = &Pl[wave * 16 * 72];

  auto step = [&](const bf16x8* qf, f32x4* o, float* Mx, float* L, bool diag) {
    f32x4 s4[4] = {};
#pragma unroll
    for (int nt = 0; nt < 4; ++nt) {
      int key = nt * 16 + li;
#pragma unroll
      for (int kc = 0; kc < 4; ++kc) {
        bf16x8 kf = *(const bf16x8*)&Kl[key * 128 + (((kc * 4 + quad) ^ (key & 7)) << 3)];
        s4[nt] = __builtin_amdgcn_mfma_f32_16x16x32_bf16(qf[kc], kf, s4[nt], 0, 0, 0);
      }
    }
    float sv[4][4];
#pragma unroll
    for (int nt = 0; nt < 4; ++nt)
#pragma unroll
      for (int r = 0; r < 4; ++r) {
        float v = s4[nt][r] * SCALE;
        if (diag && (nt * 16 + li > wave * 16 + quad * 4 + r)) v = -1e30f;
        sv[nt][r] = v;
      }
    float al[4];
#pragma unroll
    for (int r = 0; r < 4; ++r) {
      float m = fmaxf(fmaxf(sv[0][r], sv[1][r]), fmaxf(sv[2][r], sv[3][r]));
#pragma unroll
      for (int off = 1; off < 16; off <<= 1) m = fmaxf(m, __shfl_xor(m, off));
      float nm = fmaxf(Mx[r], m);
      al[r] = __expf(Mx[r] - nm);
      Mx[r] = nm;
      float s0 = 0.f;
#pragma unroll
      for (int nt = 0; nt < 4; ++nt) {
        sv[nt][r] = __expf(sv[nt][r] - nm);
        s0 += sv[nt][r];
      }
#pragma unroll
      for (int off = 1; off < 16; off <<= 1) s0 += __shfl_xor(s0, off);
      L[r] = L[r] * al[r] + s0;
    }
#pragma unroll
    for (int u = 0; u < 8; ++u)
#pragma unroll
      for (int r = 0; r < 4; ++r) o[u][r] *= al[r];
    // P: C-layout -> LDS -> A-layout (per-wave region; same-wave DS in-order)
#pragma unroll
    for (int nt = 0; nt < 4; ++nt)
#pragma unroll
      for (int r = 0; r < 4; ++r)
        Pw[(quad * 4 + r) * 72 + nt * 16 + li] = (bf16)sv[nt][r];
#pragma unroll
    for (int kc = 0; kc < 2; ++kc) {
      bf16x8 pf = *(const bf16x8*)&Pw[li * 72 + kc * 32 + quad * 8];
#pragma unroll
      for (int u = 0; u < 8; ++u) {
        bf16x8 vf = *(const bf16x8*)&Vl[(u * 16 + li) * 64 + (((kc * 4 + quad) ^ (li & 7)) << 3)];
        o[u] = __builtin_amdgcn_mfma_f32_16x16x32_bf16(pf, vf, o[u], 0, 0, 0);
      }
    }
  };

  for (int kt = 0; kt <= qtB; ++kt) {
    const int k0 = kt * 64;
    __syncthreads();  // prev iter's LDS reads done
    // stage K tile [64 k][128 d], 16B-chunk XOR swizzle
#pragma unroll
    for (int j = 0; j < 4; ++j) {
      int c = j * 256 + tid;
      int r = c >> 4, cc = c & 15;
      gl_lds16(Kg + ((size_t)bh * Tt + k0 + r) * Dd + ((cc ^ (r & 7)) << 3), &Kl[c * 8]);
    }
    // stage V^T tile [128 d][64 k], swizzled
#pragma unroll
    for (int j = 0; j < 4; ++j) {
      int c = j * 256 + tid;
      int r = c >> 3, cc = c & 7;
      gl_lds16(VgT + ((size_t)bh * Dd + r) * Tt + k0 + ((cc ^ (r & 7)) << 3), &Vl[c * 8]);
    }
    __syncthreads();

    step(qfB, oB, MxB, LB, kt == qtB);
    if (kt <= qtA) step(qfA, oA, MxA, LA, kt == qtA);
  }

  auto epi = [&](f32x4* o, float* L, int qt) {
    float inv[4];
#pragma unroll
    for (int r = 0; r < 4; ++r) inv[r] = 1.0f / L[r];
    int trow = qt * 64 + wave * 16 + quad * 4;
#pragma unroll
    for (int u = 0; u < 8; ++u) {
      int col = h * Dd + u * 16 + li;
#pragma unroll
      for (int r = 0; r < 4; ++r)
        Yg[(size_t)(b * Tt + trow + r) * Cc_ + col] = (bf16)(o[u][r] * inv[r]);
    }
  };
  epi(oA, LA, qtA);
  epi(oB, LB, qtB);
}

// ------------------------------------------------------------------ launch
extern "C" void kernel_launch(void* const* d_in, const int* in_sizes, int n_in,
                              void* d_out, int out_size, void* d_ws, size_t ws_size,
                              hipStream_t stream) {
  const float* x      = (const float*)d_in[0];
  const float* w_qkv  = (const float*)d_in[1];
  const float* w_proj = (const float*)d_in[2];
  const float* qnw    = (const float*)d_in[3];
  const float* knw    = (const float*)d_in[4];
  float* out = (float*)d_out;

  // workspace partition (bf16 elements)
  bf16* xb     = (bf16*)d_ws;                   // 8.4M el — dead after qkv GEMM
  bf16* wqkvT  = xb + (size_t)Mm_ * Cc_;
  bf16* wprojT = wqkvT + (size_t)N1 * Cc_;
  bf16* qkv    = wprojT + (size_t)Cc_ * Cc_;    // 25.2M el — dead after norm_rope
  bf16* Qg     = qkv + (size_t)Mm_ * N1;
  bf16* Kg     = Qg + (size_t)Bb * Hh * Tt * Dd;
  bf16* Vg     = Kg + (size_t)Bb * Hh * Tt * Dd;
  bf16* VgT    = xb;    // alias: 8.4M el, exactly xb's size
  bf16* Yg     = qkv;   // alias: 8.4M el into qkv's 25.2M

  hipLaunchKernelGGL(cvt_bf16, dim3((Mm_ * Cc_ / 4) / 256), dim3(256), 0, stream,
                     x, xb, Mm_ * Cc_);
  hipLaunchKernelGGL(transpose_cvt, dim3(N1 / 64, Cc_ / 64), dim3(256), 0, stream,
                     w_qkv, wqkvT, Cc_, N1);
  hipLaunchKernelGGL(transpose_cvt, dim3(Cc_ / 64, Cc_ / 64), dim3(256), 0, stream,
                     w_proj, wprojT, Cc_, Cc_);
  hipLaunchKernelGGL(gemm_bf16<bf16>, dim3(N1 / 128, Mm_ / 128), dim3(256), 0, stream,
                     xb, wqkvT, qkv, N1, Cc_);
  hipLaunchKernelGGL(norm_rope_rearrange, dim3(Bb * Tt * Hh / 4), dim3(256), 0, stream,
                     qkv, qnw, knw, Qg, Kg, Vg);
  hipLaunchKernelGGL(vtrans, dim3(Tt / 64, Dd / 64, Bb * Hh), dim3(256), 0, stream,
                     Vg, VgT);
  hipLaunchKernelGGL(attn, dim3(Bb * Hh, Tt / 128), dim3(256), 0, stream,
                     Qg, Kg, VgT, Yg);
  hipLaunchKernelGGL(gemm_bf16<float>, dim3(Cc_ / 128, Mm_ / 128), dim3(256), 0, stream,
                     Yg, wprojT, out, Cc_, Cc_);
}

// Round 3
// 386.635 us; speedup vs baseline: 1.3264x; 1.1806x over previous
//
#include <hip/hip_runtime.h>
#include <stdint.h>

#define Bb   2
#define Tt   2048
#define Cc_  2048
#define Hh   16
#define Dd   128
#define Mm_  4096            // B*T
#define N1   6144            // 3*C
#define EPSf 1.1920929e-07f
#define SCALE (1.0f/128.0f)  // reference uses 1/D, not 1/sqrt(D)

typedef __bf16 bf16;
typedef __attribute__((ext_vector_type(8))) __bf16 bf16x8;
typedef __attribute__((ext_vector_type(4))) float  f32x4;

// ---- async global->LDS, width 16. LDS dest = wave-uniform base + lane*16.
__device__ __forceinline__ void gl_lds16(const bf16* g, bf16* l) {
  __builtin_amdgcn_global_load_lds(
      (const __attribute__((address_space(1))) unsigned int*)g,
      (__attribute__((address_space(3))) unsigned int*)l, 16, 0, 0);
}

// ------------------------------------------------------------------ cvt x->bf16
__global__ __launch_bounds__(256) void cvt_bf16(const float* __restrict__ in,
                                                bf16* __restrict__ out, int n) {
  int i = (blockIdx.x * 256 + threadIdx.x) * 4;
  if (i >= n) return;
  float4 v = *(const float4*)(in + i);
  union { bf16 h[4]; uint2 u; } o;
  o.h[0] = (bf16)v.x; o.h[1] = (bf16)v.y; o.h[2] = (bf16)v.z; o.h[3] = (bf16)v.w;
  *(uint2*)(out + i) = o.u;
}

// -------------------------------------------- transpose+convert: [R][Cc]f32 -> [Cc][R]bf16
__global__ __launch_bounds__(256) void transpose_cvt(const float* __restrict__ in,
                                                     bf16* __restrict__ out,
                                                     int R, int Cc) {
  __shared__ float tile[64][65];
  int c0 = blockIdx.x * 64, r0 = blockIdx.y * 64;
  int tid = threadIdx.x;
#pragma unroll
  for (int j = 0; j < 16; ++j) {
    int idx = tid + j * 256;
    int r = idx >> 6, c = idx & 63;
    tile[r][c] = in[(size_t)(r0 + r) * Cc + c0 + c];
  }
  __syncthreads();
#pragma unroll
  for (int j = 0; j < 16; ++j) {
    int idx = tid + j * 256;
    int rr = idx & 63, cc = idx >> 6;
    out[(size_t)(c0 + cc) * R + r0 + rr] = (bf16)tile[rr][cc];
  }
}

// ----------------------------------- V transpose: [bh][T][D] -> [bh][D][T] bf16
__global__ __launch_bounds__(256) void vtrans(const bf16* __restrict__ V,
                                              bf16* __restrict__ Vt_) {
  __shared__ bf16 tile[64][72];
  int bh = blockIdx.z, t0 = blockIdx.x * 64, d0 = blockIdx.y * 64;
  int tid = threadIdx.x;
#pragma unroll
  for (int j = 0; j < 2; ++j) {
    int idx = (j * 256 + tid) * 8;
    int r = idx >> 6, c = idx & 63;
    bf16x8 v = *(const bf16x8*)(V + ((size_t)bh * Tt + t0 + r) * Dd + d0 + c);
#pragma unroll
    for (int e = 0; e < 8; ++e) tile[r][c + e] = v[e];
  }
  __syncthreads();
#pragma unroll
  for (int j = 0; j < 2; ++j) {
    int idx = (j * 256 + tid) * 8;
    int dd = idx >> 6, tt = idx & 63;
    bf16x8 v;
#pragma unroll
    for (int e = 0; e < 8; ++e) v[e] = tile[tt + e][dd];
    *(bf16x8*)(Vt_ + ((size_t)bh * Dd + d0 + dd) * Tt + t0 + tt) = v;
  }
}

// ------------------------------------------------------------------ GEMM
// C[M][N] = A[M][K] * Bt[N][K]^T, bf16 in, OutT out. 128x128 tile, BK=64.
template <typename OutT>
__global__ __launch_bounds__(256) void gemm_bf16(const bf16* __restrict__ A,
                                                 const bf16* __restrict__ Bt,
                                                 OutT* __restrict__ Cm,
                                                 int Nn, int Kk) {
  __shared__ __align__(16) bf16 As[128 * 64];
  __shared__ __align__(16) bf16 Bs[128 * 64];
  const int tid = threadIdx.x;
  const int wave = tid >> 6, lane = tid & 63;
  const int quad = lane >> 4, li = lane & 15;
  const int wm = wave >> 1, wn = wave & 1;
  const int m0 = blockIdx.y * 128, n0 = blockIdx.x * 128;

  f32x4 acc[4][4] = {};

  for (int kt = 0; kt < Kk; kt += 64) {
    __syncthreads();
#pragma unroll
    for (int j = 0; j < 4; ++j) {
      int c = j * 256 + tid;
      int r = c >> 3, cc = c & 7;
      int gc = ((cc ^ (r & 7)) << 3);
      gl_lds16(A + (size_t)(m0 + r) * Kk + kt + gc, &As[c * 8]);
      gl_lds16(Bt + (size_t)(n0 + r) * Kk + kt + gc, &Bs[c * 8]);
    }
    __syncthreads();
#pragma unroll
    for (int kc = 0; kc < 2; ++kc) {
      bf16x8 af[4], bfr[4];
#pragma unroll
      for (int t = 0; t < 4; ++t) {
        int rowa = wm * 64 + t * 16 + li;
        af[t] = *(const bf16x8*)&As[rowa * 64 + (((kc * 4 + quad) ^ (rowa & 7)) << 3)];
        int rowb = wn * 64 + t * 16 + li;
        bfr[t] = *(const bf16x8*)&Bs[rowb * 64 + (((kc * 4 + quad) ^ (rowb & 7)) << 3)];
      }
#pragma unroll
      for (int mi = 0; mi < 4; ++mi)
#pragma unroll
        for (int ni = 0; ni < 4; ++ni)
          acc[mi][ni] = __builtin_amdgcn_mfma_f32_16x16x32_bf16(af[mi], bfr[ni],
                                                                acc[mi][ni], 0, 0, 0);
    }
  }
#pragma unroll
  for (int mi = 0; mi < 4; ++mi) {
    int row = m0 + wm * 64 + mi * 16 + quad * 4;
#pragma unroll
    for (int ni = 0; ni < 4; ++ni) {
      int col = n0 + wn * 64 + ni * 16 + li;
#pragma unroll
      for (int r = 0; r < 4; ++r)
        Cm[(size_t)(row + r) * Nn + col] = (OutT)acc[mi][ni][r];
    }
  }
}

// ------------------------------------------- RMSNorm + RoPE + rearrange
__global__ __launch_bounds__(256) void norm_rope_rearrange(
    const bf16* __restrict__ qkv, const float* __restrict__ qw,
    const float* __restrict__ kw, bf16* __restrict__ Qg,
    bf16* __restrict__ Kg, bf16* __restrict__ Vg) {
  int unit = blockIdx.x * 4 + (threadIdx.x >> 6);  // (b*T + t)*H + h
  int lane = threadIdx.x & 63;
  int h = unit & 15;
  int bt = unit >> 4;
  int t = bt & 2047, b = bt >> 11;
  const bf16* base = qkv + (size_t)bt * N1 + h * Dd;
  float q1 = (float)base[lane], q2 = (float)base[lane + 64];
  float k1 = (float)base[Cc_ + lane], k2 = (float)base[Cc_ + lane + 64];
  float v1 = (float)base[2 * Cc_ + lane], v2 = (float)base[2 * Cc_ + lane + 64];
  float sq = q1 * q1 + q2 * q2;
  float sk = k1 * k1 + k2 * k2;
#pragma unroll
  for (int o = 1; o < 64; o <<= 1) { sq += __shfl_xor(sq, o); sk += __shfl_xor(sk, o); }
  float rq = rsqrtf(sq * (1.0f / 128.0f) + EPSf);
  float rk = rsqrtf(sk * (1.0f / 128.0f) + EPSf);
  q1 *= rq * qw[lane]; q2 *= rq * qw[lane + 64];
  k1 *= rk * kw[lane]; k2 *= rk * kw[lane + 64];
  float invf = exp2f((float)lane * (-19.9315685693241740f / 64.0f));
  float ang = (float)t * invf;
  float sn, cs;
  sincosf(ang, &sn, &cs);
  float qo1 = q1 * cs - q2 * sn, qo2 = q2 * cs + q1 * sn;
  float ko1 = k1 * cs - k2 * sn, ko2 = k2 * cs + k1 * sn;
  size_t o1 = ((size_t)(b * Hh + h) * Tt + t) * Dd + lane;
  Qg[o1] = (bf16)qo1; Qg[o1 + 64] = (bf16)qo2;
  Kg[o1] = (bf16)ko1; Kg[o1 + 64] = (bf16)ko2;
  Vg[o1] = (bf16)v1;  Vg[o1 + 64] = (bf16)v2;
}

// ------------------------------------------------------------------ attention
// Single q-tile per block, grid 32bh x 32qt (qt descending), 1024 blocks.
// Exact-bound softmax: q,k RMS-normed (w=1) + RoPE norm-preserving + scale
// 1/128 => |s| <= ~1.01 (Cauchy-Schwarz). No max tracking, no per-step
// reductions, no o-rescale; L accumulated per-lane, reduced ONCE at the end.
__global__ __launch_bounds__(256, 3) void attn(const bf16* __restrict__ Qg,
                                               const bf16* __restrict__ Kg,
                                               const bf16* __restrict__ VgT,
                                               bf16* __restrict__ Yg) {
  __shared__ __align__(16) bf16 Kl[64 * 128];
  __shared__ __align__(16) bf16 Vl[128 * 64];
  __shared__ __align__(16) bf16 Pl[4 * 16 * 72];
  const int bh = blockIdx.x;
  const int qt = (int)gridDim.y - 1 - (int)blockIdx.y;  // long blocks first
  const int b = bh >> 4, h = bh & 15;
  const int tid = threadIdx.x, wave = tid >> 6, lane = tid & 63;
  const int quad = lane >> 4, li = lane & 15;
  const int q0 = qt * 64;

  // Q fragments (A-layout) straight from global, held for whole block
  const bf16* Qbase = Qg + ((size_t)bh * Tt + q0 + wave * 16 + li) * Dd;
  bf16x8 qf[4];
#pragma unroll
  for (int kc = 0; kc < 4; ++kc) qf[kc] = *(const bf16x8*)(Qbase + kc * 32 + quad * 8);

  f32x4 o[8] = {};
  float L[4] = {};
  bf16* Pw = &Pl[wave * 16 * 72];

  for (int kt = 0; kt <= qt; ++kt) {
    const int k0 = kt * 64;
    __syncthreads();  // prev iter's LDS reads done
    // stage K tile [64 k][128 d], 16B-chunk XOR swizzle
#pragma unroll
    for (int j = 0; j < 4; ++j) {
      int c = j * 256 + tid;
      int r = c >> 4, cc = c & 15;
      gl_lds16(Kg + ((size_t)bh * Tt + k0 + r) * Dd + ((cc ^ (r & 7)) << 3), &Kl[c * 8]);
    }
    // stage V^T tile [128 d][64 k], swizzled
#pragma unroll
    for (int j = 0; j < 4; ++j) {
      int c = j * 256 + tid;
      int r = c >> 3, cc = c & 7;
      gl_lds16(VgT + ((size_t)bh * Dd + r) * Tt + k0 + ((cc ^ (r & 7)) << 3), &Vl[c * 8]);
    }
    __syncthreads();

    // QK^T
    f32x4 s4[4] = {};
#pragma unroll
    for (int nt = 0; nt < 4; ++nt) {
      int key = nt * 16 + li;
#pragma unroll
      for (int kc = 0; kc < 4; ++kc) {
        bf16x8 kf = *(const bf16x8*)&Kl[key * 128 + (((kc * 4 + quad) ^ (key & 7)) << 3)];
        s4[nt] = __builtin_amdgcn_mfma_f32_16x16x32_bf16(qf[kc], kf, s4[nt], 0, 0, 0);
      }
    }
    // exp (no max needed: |s|<=1.01), mask, per-lane L accumulate, pack P
    const bool diag = (kt == qt);
#pragma unroll
    for (int nt = 0; nt < 4; ++nt)
#pragma unroll
      for (int r = 0; r < 4; ++r) {
        float e = __expf(s4[nt][r] * SCALE);
        if (diag && (nt * 16 + li > wave * 16 + quad * 4 + r)) e = 0.f;
        L[r] += e;
        Pw[(quad * 4 + r) * 72 + nt * 16 + li] = (bf16)e;
      }
    // PV: o[16 q][128 d] += P[16][64] * V[64][128]
#pragma unroll
    for (int kc = 0; kc < 2; ++kc) {
      bf16x8 pf = *(const bf16x8*)&Pw[li * 72 + kc * 32 + quad * 8];
#pragma unroll
      for (int u = 0; u < 8; ++u) {
        bf16x8 vf = *(const bf16x8*)&Vl[(u * 16 + li) * 64 + (((kc * 4 + quad) ^ (li & 7)) << 3)];
        o[u] = __builtin_amdgcn_mfma_f32_16x16x32_bf16(pf, vf, o[u], 0, 0, 0);
      }
    }
  }

  // single final row-sum reduction (width 16) + normalize + write
  float inv[4];
#pragma unroll
  for (int r = 0; r < 4; ++r) {
    float s0 = L[r];
#pragma unroll
    for (int off = 1; off < 16; off <<= 1) s0 += __shfl_xor(s0, off);
    inv[r] = 1.0f / s0;
  }
  int trow = q0 + wave * 16 + quad * 4;
#pragma unroll
  for (int u = 0; u < 8; ++u) {
    int col = h * Dd + u * 16 + li;
#pragma unroll
    for (int r = 0; r < 4; ++r)
      Yg[(size_t)(b * Tt + trow + r) * Cc_ + col] = (bf16)(o[u][r] * inv[r]);
  }
}

// ------------------------------------------------------------------ launch
extern "C" void kernel_launch(void* const* d_in, const int* in_sizes, int n_in,
                              void* d_out, int out_size, void* d_ws, size_t ws_size,
                              hipStream_t stream) {
  const float* x      = (const float*)d_in[0];
  const float* w_qkv  = (const float*)d_in[1];
  const float* w_proj = (const float*)d_in[2];
  const float* qnw    = (const float*)d_in[3];
  const float* knw    = (const float*)d_in[4];
  float* out = (float*)d_out;

  // workspace partition (bf16 elements)
  bf16* xb     = (bf16*)d_ws;                   // dead after qkv GEMM
  bf16* wqkvT  = xb + (size_t)Mm_ * Cc_;
  bf16* wprojT = wqkvT + (size_t)N1 * Cc_;
  bf16* qkv    = wprojT + (size_t)Cc_ * Cc_;    // dead after norm_rope
  bf16* Qg     = qkv + (size_t)Mm_ * N1;
  bf16* Kg     = Qg + (size_t)Bb * Hh * Tt * Dd;
  bf16* Vg     = Kg + (size_t)Bb * Hh * Tt * Dd;
  bf16* VgT    = xb;    // alias: exactly xb's size
  bf16* Yg     = qkv;   // alias into qkv's region

  hipLaunchKernelGGL(cvt_bf16, dim3((Mm_ * Cc_ / 4) / 256), dim3(256), 0, stream,
                     x, xb, Mm_ * Cc_);
  hipLaunchKernelGGL(transpose_cvt, dim3(N1 / 64, Cc_ / 64), dim3(256), 0, stream,
                     w_qkv, wqkvT, Cc_, N1);
  hipLaunchKernelGGL(transpose_cvt, dim3(Cc_ / 64, Cc_ / 64), dim3(256), 0, stream,
                     w_proj, wprojT, Cc_, Cc_);
  hipLaunchKernelGGL(gemm_bf16<bf16>, dim3(N1 / 128, Mm_ / 128), dim3(256), 0, stream,
                     xb, wqkvT, qkv, N1, Cc_);
  hipLaunchKernelGGL(norm_rope_rearrange, dim3(Bb * Tt * Hh / 4), dim3(256), 0, stream,
                     qkv, qnw, knw, Qg, Kg, Vg);
  hipLaunchKernelGGL(vtrans, dim3(Tt / 64, Dd / 64, Bb * Hh), dim3(256), 0, stream,
                     Vg, VgT);
  hipLaunchKernelGGL(attn, dim3(Bb * Hh, Tt / 64), dim3(256), 0, stream,
                     Qg, Kg, VgT, Yg);
  hipLaunchKernelGGL(gemm_bf16<float>, dim3(Cc_ / 128, Mm_ / 128), dim3(256), 0, stream,
                     Yg, wprojT, out, Cc_, Cc_);
}